// Round 3
// baseline (1001.147 us; speedup 1.0000x reference)
//
#include <hip/hip_runtime.h>
#include <hip/hip_bf16.h>

#define F1   128   // F_IN and HEADS*HID
#define H1   4     // conv1 heads
#define C2   40    // classes
#define NEG  0.2f  // leaky relu slope

typedef __hip_bfloat16 bf16;

// dtype-flexible load: isbf ? bf16[i] : fp32[i]
__device__ __forceinline__ float ldf(const void* p, size_t i, int isbf) {
    return isbf ? __bfloat162float(((const bf16*)p)[i]) : ((const float*)p)[i];
}

__device__ __forceinline__ void edge_sd(const int* __restrict__ ei, int E, int e,
                                        int& s, int& d) {
    if (e < E) { s = ei[e]; d = ei[E + e]; }
    else       { s = e - E; d = e - E; }   // self-loop
}

__device__ __forceinline__ float lrelu(float a) { return a > 0.f ? a : NEG * a; }

// K0: detect dtype of x. bf16 N(0,1): u16 exponent field <=130 always.
// fp32 N(0,1): low mantissa halves have ~uniform exponent field -> ~19% >=160.
__global__ void k_detect(const unsigned short* __restrict__ x, int* __restrict__ flag) {
    __shared__ int sh[256];
    int cnt = 0;
    for (int i = threadIdx.x; i < 8192; i += 256) {
        int e = (x[i] >> 7) & 0xFF;
        if (e >= 160) cnt++;
    }
    sh[threadIdx.x] = cnt;
    __syncthreads();
    for (int s = 128; s > 0; s >>= 1) {
        if (threadIdx.x < s) sh[threadIdx.x] += sh[threadIdx.x + s];
        __syncthreads();
    }
    if (threadIdx.x == 0) flag[0] = (sh[0] < 100) ? 1 : 0;   // 1 = bf16, 0 = fp32
}

// K1: h1 = x @ W1 (fp32); e_src1/e_dst1 per-head attention scores [N,4]
__global__ void k_gemm1(const void* __restrict__ x, const void* __restrict__ W1,
                        const void* __restrict__ as1, const void* __restrict__ ad1,
                        const int* __restrict__ flag,
                        float* __restrict__ h1, float* __restrict__ e_src,
                        float* __restrict__ e_dst) {
    const int isbf = flag[0];
    __shared__ float xs[F1];
    int n = blockIdx.x, t = threadIdx.x;
    xs[t] = ldf(x, (size_t)n * F1 + t, isbf);
    __syncthreads();
    float acc = 0.f;
#pragma unroll 8
    for (int k = 0; k < F1; k++) acc = fmaf(xs[k], ldf(W1, (size_t)k * F1 + t, isbf), acc);
    h1[(size_t)n * F1 + t] = acc;
    // attention scores: reduce within each 32-lane head group
    float s = acc * ldf(as1, t, isbf);
    float d = acc * ldf(ad1, t, isbf);
#pragma unroll
    for (int off = 16; off > 0; off >>= 1) {
        s += __shfl_down(s, off, 32);
        d += __shfl_down(d, off, 32);
    }
    if ((t & 31) == 0) {
        int h = t >> 5;
        e_src[n * H1 + h] = s;
        e_dst[n * H1 + h] = d;
    }
}

// K2: denom1[d,h] += exp(lrelu(es[s,h]+ed[d,h]))   (softmax shift-invariant; no max)
__global__ void k_denom1(const int* __restrict__ ei, int E, int ET,
                         const float* __restrict__ es, const float* __restrict__ ed,
                         float* __restrict__ denom) {
    int idx = blockIdx.x * blockDim.x + threadIdx.x;
    if (idx >= ET * H1) return;
    int e = idx >> 2, h = idx & 3, s, d;
    edge_sd(ei, E, e, s, d);
    float ex = __expf(lrelu(es[s * H1 + h] + ed[d * H1 + h]));
    atomicAdd(&denom[d * H1 + h], ex);
}

// K3: agg1[d,col] += h1[s,col] * exp(alpha)/denom   (thread per edge-column)
__global__ void k_agg1(const int* __restrict__ ei, int E, int ET,
                       const float* __restrict__ es, const float* __restrict__ ed,
                       const float* __restrict__ denom, const float* __restrict__ h1,
                       float* __restrict__ agg) {
    int idx = blockIdx.x * blockDim.x + threadIdx.x;
    if (idx >= ET * F1) return;
    int e = idx >> 7, col = idx & 127, h = col >> 5, s, d;
    edge_sd(ei, E, e, s, d);
    float ex = __expf(lrelu(es[s * H1 + h] + ed[d * H1 + h]));
    float coef = ex / (denom[d * H1 + h] + 1e-16f);
    atomicAdd(&agg[(size_t)d * F1 + col], h1[(size_t)s * F1 + col] * coef);
}

// K4: h_mid = elu(agg1 + bias1); h2 = h_mid @ W2 [N,40]; e_src2/e_dst2 [N]
__global__ void k_layer2_prep(const float* __restrict__ agg1, const void* __restrict__ b1,
                              const void* __restrict__ W2, const void* __restrict__ as2,
                              const void* __restrict__ ad2, const int* __restrict__ flag,
                              float* __restrict__ h2,
                              float* __restrict__ es2, float* __restrict__ ed2) {
    const int isbf = flag[0];
    __shared__ float hs[F1];
    __shared__ float h2s[C2];
    int n = blockIdx.x, t = threadIdx.x;
    float v = agg1[(size_t)n * F1 + t] + ldf(b1, t, isbf);
    v = v > 0.f ? v : (__expf(v) - 1.f);   // ELU
    hs[t] = v;
    __syncthreads();
    if (t < C2) {
        float acc = 0.f;
#pragma unroll 8
        for (int k = 0; k < F1; k++) acc = fmaf(hs[k], ldf(W2, (size_t)k * C2 + t, isbf), acc);
        h2[(size_t)n * C2 + t] = acc;
        h2s[t] = acc;
    }
    __syncthreads();
    if (t == 0) {
        float es = 0.f, ed = 0.f;
        for (int c = 0; c < C2; c++) {
            es = fmaf(h2s[c], ldf(as2, c, isbf), es);
            ed = fmaf(h2s[c], ldf(ad2, c, isbf), ed);
        }
        es2[n] = es;
        ed2[n] = ed;
    }
}

// K5: layer-2 denominators (single head)
__global__ void k_denom2(const int* __restrict__ ei, int E, int ET,
                         const float* __restrict__ es, const float* __restrict__ ed,
                         float* __restrict__ denom) {
    int e = blockIdx.x * blockDim.x + threadIdx.x;
    if (e >= ET) return;
    int s, d;
    edge_sd(ei, E, e, s, d);
    atomicAdd(&denom[d], __expf(lrelu(es[s] + ed[d])));
}

// K6: agg2[d,c] += h2[s,c] * coef  (thread per edge-class)
__global__ void k_agg2(const int* __restrict__ ei, int E, int ET,
                       const float* __restrict__ es, const float* __restrict__ ed,
                       const float* __restrict__ denom, const float* __restrict__ h2,
                       float* __restrict__ agg) {
    int idx = blockIdx.x * blockDim.x + threadIdx.x;
    if (idx >= ET * C2) return;
    unsigned e = (unsigned)idx / C2;          // const-divisor -> mul_hi
    int c = idx - (int)e * C2;
    int s, d;
    edge_sd(ei, E, (int)e, s, d);
    float ex = __expf(lrelu(es[s] + ed[d]));
    float coef = ex / (denom[d] + 1e-16f);
    atomicAdd(&agg[(size_t)d * C2 + c], h2[(size_t)s * C2 + c] * coef);
}

// K7: out = (log_softmax, softmax) over 40 classes; dtype per flag
__global__ void k_out(const float* __restrict__ agg2, const void* __restrict__ b2,
                      const int* __restrict__ flag, void* __restrict__ out, int N) {
    const int isbf = flag[0];
    int n = blockIdx.x * blockDim.x + threadIdx.x;
    if (n >= N) return;
    float v[C2];
    float m = -1e30f;
#pragma unroll
    for (int c = 0; c < C2; c++) {
        v[c] = agg2[(size_t)n * C2 + c] + ldf(b2, c, isbf);
        m = fmaxf(m, v[c]);
    }
    float sum = 0.f;
#pragma unroll
    for (int c = 0; c < C2; c++) sum += __expf(v[c] - m);
    float lse = m + __logf(sum);
    size_t base = (size_t)n * C2, half = (size_t)N * C2;
#pragma unroll
    for (int c = 0; c < C2; c++) {
        float ls = v[c] - lse;
        float sm = __expf(ls);
        if (isbf) {
            ((bf16*)out)[base + c]        = __float2bfloat16(ls);
            ((bf16*)out)[half + base + c] = __float2bfloat16(sm);
        } else {
            ((float*)out)[base + c]        = ls;
            ((float*)out)[half + base + c] = sm;
        }
    }
}

extern "C" void kernel_launch(void* const* d_in, const int* in_sizes, int n_in,
                              void* d_out, int out_size, void* d_ws, size_t ws_size,
                              hipStream_t stream) {
    const int N  = in_sizes[0] / F1;
    const int E  = in_sizes[1] / 2;
    const int ET = E + N;  // edges + self-loops

    const void* x   = d_in[0];
    const int*  ei  = (const int*)d_in[1];
    const void* W1  = d_in[2];
    const void* as1 = d_in[3];
    const void* ad1 = d_in[4];
    const void* b1  = d_in[5];
    const void* W2  = d_in[6];
    const void* as2 = d_in[7];
    const void* ad2 = d_in[8];
    const void* b2  = d_in[9];

    // ---- workspace layout (float slots), peak = 268N floats + flag = 53.6 MB ----
    float* ws = (float*)d_ws;
    float*  agg1   = ws;                          // [0, 128N)   zeroed
    float*  denom1 = ws + (size_t)128 * N;        // [128N,132N) zeroed
    float*  h1     = ws + (size_t)132 * N;        // [132N,260N)
    float*  es1    = ws + (size_t)260 * N;        // [260N,264N)
    float*  ed1    = ws + (size_t)264 * N;        // [264N,268N)
    int*    flag   = (int*)(ws + (size_t)268 * N);
    // layer-2 overlays (hosts dead by the time these are written):
    float*  agg2   = ws;                          // over agg1 [0, 40N)
    float*  denom2 = ws + (size_t)40 * N;         // over agg1 [40N, 41N)
    float*  h2     = ws + (size_t)132 * N;        // over h1   [132N, 172N)
    float*  es2    = ws + (size_t)172 * N;        // over h1   [172N, 173N)
    float*  ed2    = ws + (size_t)173 * N;        // over h1   [173N, 174N)

    const int T = 256;
    k_detect<<<1, 256, 0, stream>>>((const unsigned short*)x, flag);
    hipMemsetAsync(agg1, 0, (size_t)132 * N * sizeof(float), stream);

    k_gemm1<<<N, F1, 0, stream>>>(x, W1, as1, ad1, flag, h1, es1, ed1);
    k_denom1<<<(ET * H1 + T - 1) / T, T, 0, stream>>>(ei, E, ET, es1, ed1, denom1);
    k_agg1<<<(int)(((size_t)ET * F1 + T - 1) / T), T, 0, stream>>>(ei, E, ET, es1, ed1,
                                                                   denom1, h1, agg1);
    k_layer2_prep<<<N, F1, 0, stream>>>(agg1, b1, W2, as2, ad2, flag, h2, es2, ed2);
    // agg1/denom1 now dead: zero agg2 + denom2 (contiguous [0, 41N))
    hipMemsetAsync(agg2, 0, (size_t)41 * N * sizeof(float), stream);
    k_denom2<<<(ET + T - 1) / T, T, 0, stream>>>(ei, E, ET, es2, ed2, denom2);
    k_agg2<<<(ET * C2 + T - 1) / T, T, 0, stream>>>(ei, E, ET, es2, ed2, denom2, h2, agg2);
    k_out<<<(N + T - 1) / T, T, 0, stream>>>(agg2, b2, flag, d_out, N);
}

// Round 4
// 571.186 us; speedup vs baseline: 1.7528x; 1.7528x over previous
//
#include <hip/hip_runtime.h>
#include <hip/hip_bf16.h>

#define F1   128   // F_IN and HEADS*HID
#define H1   4     // conv1 heads
#define C2   40    // classes
#define NEG  0.2f  // leaky relu slope
#define BN   8     // gemm1 nodes per block

typedef __hip_bfloat16 bf16;

// dtype-flexible load: isbf ? bf16[i] : fp32[i]
__device__ __forceinline__ float ldf(const void* p, size_t i, int isbf) {
    return isbf ? __bfloat162float(((const bf16*)p)[i]) : ((const float*)p)[i];
}
__device__ __forceinline__ float lrelu(float a) { return a > 0.f ? a : NEG * a; }

__device__ __forceinline__ void edge_sd(const int* __restrict__ ei, int E, int e,
                                        int& s, int& d) {
    if (e < E) { s = ei[e]; d = ei[E + e]; }
    else       { s = e - E; d = e - E; }   // self-loop
}

// K0: dtype detect (bf16 N(0,1): u16 exp field never >=160; fp32: ~19% of words)
__global__ void k_detect(const unsigned short* __restrict__ x, int* __restrict__ flag) {
    __shared__ int sh[256];
    int cnt = 0;
    for (int i = threadIdx.x; i < 8192; i += 256)
        if (((x[i] >> 7) & 0xFF) >= 160) cnt++;
    sh[threadIdx.x] = cnt;
    __syncthreads();
    for (int s = 128; s > 0; s >>= 1) {
        if (threadIdx.x < s) sh[threadIdx.x] += sh[threadIdx.x + s];
        __syncthreads();
    }
    if (threadIdx.x == 0) flag[0] = (sh[0] < 100) ? 1 : 0;   // 1=bf16, 0=fp32
}

// K1: h1 = x @ W1, tiled BN nodes/block (amortize W1 reads)
__global__ void k_gemm1(const void* __restrict__ x, const void* __restrict__ W1,
                        const int* __restrict__ flag, float* __restrict__ h1, int N) {
    __shared__ float xs[BN][F1];
    const int isbf = flag[0];
    int b = blockIdx.x, t = threadIdx.x;
    int n0 = b * BN;
    for (int i = t; i < BN * F1; i += 256) {
        int nn = i >> 7, kk = i & 127;
        int n = n0 + nn; if (n >= N) n = N - 1;
        xs[nn][kk] = ldf(x, (size_t)n * F1 + kk, isbf);
    }
    __syncthreads();
    int col = t & 127, nh = t >> 7;   // nh in {0,1}; thread owns nodes nh,nh+2,nh+4,nh+6
    float a0 = 0.f, a1 = 0.f, a2 = 0.f, a3 = 0.f;
    if (isbf) {
        const bf16* W = (const bf16*)W1;
#pragma unroll 4
        for (int k = 0; k < F1; k++) {
            float w = __bfloat162float(W[(size_t)k * F1 + col]);
            a0 = fmaf(xs[nh][k], w, a0);     a1 = fmaf(xs[nh + 2][k], w, a1);
            a2 = fmaf(xs[nh + 4][k], w, a2); a3 = fmaf(xs[nh + 6][k], w, a3);
        }
    } else {
        const float* W = (const float*)W1;
#pragma unroll 4
        for (int k = 0; k < F1; k++) {
            float w = W[(size_t)k * F1 + col];
            a0 = fmaf(xs[nh][k], w, a0);     a1 = fmaf(xs[nh + 2][k], w, a1);
            a2 = fmaf(xs[nh + 4][k], w, a2); a3 = fmaf(xs[nh + 6][k], w, a3);
        }
    }
    if (n0 + nh     < N) h1[(size_t)(n0 + nh)     * F1 + col] = a0;
    if (n0 + nh + 2 < N) h1[(size_t)(n0 + nh + 2) * F1 + col] = a1;
    if (n0 + nh + 4 < N) h1[(size_t)(n0 + nh + 4) * F1 + col] = a2;
    if (n0 + nh + 6 < N) h1[(size_t)(n0 + nh + 6) * F1 + col] = a3;
}

// K2: per-head attention scores for layer 1
__global__ void k_scores(const float* __restrict__ h1, const void* __restrict__ as1,
                         const void* __restrict__ ad1, const int* __restrict__ flag,
                         float* __restrict__ es1, float* __restrict__ ed1) {
    const int isbf = flag[0];
    int n = blockIdx.x, t = threadIdx.x;  // 128 threads
    float hv = h1[(size_t)n * F1 + t];
    float s = hv * ldf(as1, t, isbf);
    float d = hv * ldf(ad1, t, isbf);
#pragma unroll
    for (int off = 16; off > 0; off >>= 1) {
        s += __shfl_down(s, off, 32);
        d += __shfl_down(d, off, 32);
    }
    if ((t & 31) == 0) {
        int h = t >> 5;
        es1[n * H1 + h] = s;
        ed1[n * H1 + h] = d;
    }
}

// K3: histogram of dst degrees
__global__ void k_hist(const int* __restrict__ ei, int E, int ET, int* __restrict__ deg) {
    int e = blockIdx.x * blockDim.x + threadIdx.x;
    if (e >= ET) return;
    int s, d; edge_sd(ei, E, e, s, d);
    atomicAdd(&deg[d], 1);
}

// K4a: per-256-chunk sums
__global__ void k_scan1(const int* __restrict__ deg, int N, int* __restrict__ part) {
    __shared__ int sh[256];
    int i = blockIdx.x * 256 + threadIdx.x;
    sh[threadIdx.x] = (i < N) ? deg[i] : 0;
    __syncthreads();
    for (int s = 128; s > 0; s >>= 1) {
        if (threadIdx.x < s) sh[threadIdx.x] += sh[threadIdx.x + s];
        __syncthreads();
    }
    if (threadIdx.x == 0) part[blockIdx.x] = sh[0];
}

// K4b: exclusive scan of partials (<=256)
__global__ void k_scan2(int* __restrict__ part, int NB) {
    __shared__ int sh[256];
    int t = threadIdx.x;
    int v = (t < NB) ? part[t] : 0;
    sh[t] = v;
    __syncthreads();
    for (int off = 1; off < 256; off <<= 1) {
        int add = (t >= off) ? sh[t - off] : 0;
        __syncthreads();
        sh[t] += add;
        __syncthreads();
    }
    if (t < NB) part[t] = sh[t] - v;   // exclusive
}

// K4c: offs = exclusive scan of deg (chunk-local scan + chunk base)
__global__ void k_scan3(const int* __restrict__ deg, int N, const int* __restrict__ part,
                        int* __restrict__ offs) {
    __shared__ int sh[256];
    int t = threadIdx.x, i = blockIdx.x * 256 + t;
    int v = (i < N) ? deg[i] : 0;
    sh[t] = v;
    __syncthreads();
    for (int off = 1; off < 256; off <<= 1) {
        int add = (t >= off) ? sh[t - off] : 0;
        __syncthreads();
        sh[t] += add;
        __syncthreads();
    }
    if (i < N) offs[i] = sh[t] - v + part[blockIdx.x];
}

// K5: scatter src ids into CSR buckets. offs[d] post-increments to segment END.
// Afterwards: segment d = [ d ? offs[d-1] : 0, offs[d] ).
__global__ void k_scatter(const int* __restrict__ ei, int E, int ET,
                          int* __restrict__ offs, int* __restrict__ ebuf) {
    int e = blockIdx.x * blockDim.x + threadIdx.x;
    if (e >= ET) return;
    int s, d; edge_sd(ei, E, e, s, d);
    int pos = atomicAdd(&offs[d], 1);
    ebuf[pos] = s;
}

// K6: fused layer-1 aggregate + softmax-normalize + bias + ELU + h2 GEMM + L2 scores
__global__ void k_l1(const int* __restrict__ offs, const int* __restrict__ ebuf,
                     const float* __restrict__ h1, const float* __restrict__ es1,
                     const float* __restrict__ ed1, const void* __restrict__ b1,
                     const void* __restrict__ W2, const void* __restrict__ as2,
                     const void* __restrict__ ad2, const int* __restrict__ flag,
                     float* __restrict__ h2, float* __restrict__ es2,
                     float* __restrict__ ed2) {
    int d = blockIdx.x, t = threadIdx.x;  // 128 threads
    int h = t >> 5;
    int start = (d == 0) ? 0 : offs[d - 1];
    int end = offs[d];
    float edh = ed1[d * H1 + h];
    float acc = 0.f, dsum = 0.f;
    for (int i = start; i < end; i++) {
        int s = ebuf[i];
        float ex = __expf(lrelu(es1[s * H1 + h] + edh));
        acc = fmaf(ex, h1[(size_t)s * F1 + t], acc);
        dsum += ex;
    }
    const int isbf = flag[0];
    float v = acc / (dsum + 1e-16f) + ldf(b1, t, isbf);
    v = v > 0.f ? v : (__expf(v) - 1.f);   // ELU
    __shared__ float hs[F1];
    __shared__ float h2s[C2];
    hs[t] = v;
    __syncthreads();
    if (t < C2) {
        float a2 = 0.f;
#pragma unroll 8
        for (int k = 0; k < F1; k++) a2 = fmaf(hs[k], ldf(W2, (size_t)k * C2 + t, isbf), a2);
        h2[(size_t)d * C2 + t] = a2;
        h2s[t] = a2;
    }
    __syncthreads();
    if (t == 0) {
        float es = 0.f, ed = 0.f;
        for (int c = 0; c < C2; c++) {
            es = fmaf(h2s[c], ldf(as2, c, isbf), es);
            ed = fmaf(h2s[c], ldf(ad2, c, isbf), ed);
        }
        es2[d] = es;
        ed2[d] = ed;
    }
}

// K7: fused layer-2 aggregate + bias + log_softmax/softmax + store (one wave/node)
__global__ void k_l2(const int* __restrict__ offs, const int* __restrict__ ebuf,
                     const float* __restrict__ h2, const float* __restrict__ es2,
                     const float* __restrict__ ed2, const void* __restrict__ b2,
                     const int* __restrict__ flag, void* __restrict__ out, int N) {
    int d = blockIdx.x, t = threadIdx.x;  // 64 threads (one wave)
    int start = (d == 0) ? 0 : offs[d - 1];
    int end = offs[d];
    float edd = ed2[d];
    float acc = 0.f, dsum = 0.f;
    for (int i = start; i < end; i++) {
        int s = ebuf[i];
        float ex = __expf(lrelu(es2[s] + edd));
        if (t < C2) acc = fmaf(ex, h2[(size_t)s * C2 + t], acc);
        dsum += ex;
    }
    const int isbf = flag[0];
    float v = (t < C2) ? acc / (dsum + 1e-16f) + ldf(b2, t, isbf) : -1e30f;
    float m = v;
#pragma unroll
    for (int off = 32; off > 0; off >>= 1) m = fmaxf(m, __shfl_xor(m, off, 64));
    float ex2 = (t < C2) ? __expf(v - m) : 0.f;
    float sum = ex2;
#pragma unroll
    for (int off = 32; off > 0; off >>= 1) sum += __shfl_xor(sum, off, 64);
    float lse = m + __logf(sum);
    if (t < C2) {
        float ls = v - lse, sm = __expf(ls);
        size_t base = (size_t)d * C2 + t, half = (size_t)N * C2;
        if (isbf) {
            ((bf16*)out)[base]        = __float2bfloat16(ls);
            ((bf16*)out)[half + base] = __float2bfloat16(sm);
        } else {
            ((float*)out)[base]        = ls;
            ((float*)out)[half + base] = sm;
        }
    }
}

extern "C" void kernel_launch(void* const* d_in, const int* in_sizes, int n_in,
                              void* d_out, int out_size, void* d_ws, size_t ws_size,
                              hipStream_t stream) {
    const int N  = in_sizes[0] / F1;
    const int E  = in_sizes[1] / 2;
    const int ET = E + N;
    const int NB = (N + 255) / 256;   // scan chunks (<=256 required; N<=65536)

    const void* x   = d_in[0];
    const int*  ei  = (const int*)d_in[1];
    const void* W1  = d_in[2];
    const void* as1 = d_in[3];
    const void* ad1 = d_in[4];
    const void* b1  = d_in[5];
    const void* W2  = d_in[6];
    const void* as2 = d_in[7];
    const void* ad2 = d_in[8];
    const void* b2  = d_in[9];

    // ---- workspace: ~179N + ET + 260 floats ≈ 39 MB ----
    float* ws = (float*)d_ws;
    size_t o = 0;
    float* h1   = ws + o; o += (size_t)F1 * N;   // 128N
    float* es1  = ws + o; o += (size_t)H1 * N;
    float* ed1  = ws + o; o += (size_t)H1 * N;
    float* h2   = ws + o; o += (size_t)C2 * N;
    float* es2  = ws + o; o += N;
    float* ed2  = ws + o; o += N;
    int*   deg  = (int*)(ws + o); o += N;
    int*   offs = (int*)(ws + o); o += N;
    int*   part = (int*)(ws + o); o += 256;
    int*   flag = (int*)(ws + o); o += 4;
    int*   ebuf = (int*)(ws + o); o += ET;

    const int T = 256;
    k_detect<<<1, 256, 0, stream>>>((const unsigned short*)x, flag);
    hipMemsetAsync(deg, 0, (size_t)N * sizeof(int), stream);

    k_gemm1<<<(N + BN - 1) / BN, 256, 0, stream>>>(x, W1, flag, h1, N);
    k_scores<<<N, F1, 0, stream>>>(h1, as1, ad1, flag, es1, ed1);

    k_hist<<<(ET + T - 1) / T, T, 0, stream>>>(ei, E, ET, deg);
    k_scan1<<<NB, 256, 0, stream>>>(deg, N, part);
    k_scan2<<<1, 256, 0, stream>>>(part, NB);
    k_scan3<<<NB, 256, 0, stream>>>(deg, N, part, offs);
    k_scatter<<<(ET + T - 1) / T, T, 0, stream>>>(ei, E, ET, offs, ebuf);

    k_l1<<<N, F1, 0, stream>>>(offs, ebuf, h1, es1, ed1, b1, W2, as2, ad2, flag,
                               h2, es2, ed2);
    k_l2<<<N, 64, 0, stream>>>(offs, ebuf, h2, es2, ed2, b2, flag, d_out, N);
}

// Round 5
// 389.713 us; speedup vs baseline: 2.5689x; 1.4657x over previous
//
#include <hip/hip_runtime.h>
#include <hip/hip_bf16.h>

#define F1   128   // F_IN and HEADS*HID
#define H1   4     // conv1 heads
#define C2   40    // classes
#define NEG  0.2f  // leaky relu slope
#define BN   8     // gemm1 nodes per block

typedef __hip_bfloat16 bf16;

// dtype-flexible load: isbf ? bf16[i] : fp32[i]
__device__ __forceinline__ float ldf(const void* p, size_t i, int isbf) {
    return isbf ? __bfloat162float(((const bf16*)p)[i]) : ((const float*)p)[i];
}
__device__ __forceinline__ float lrelu(float a) { return a > 0.f ? a : NEG * a; }

// unpack packed bf16x2 (little-endian: low ushort = col 2l, high = col 2l+1)
__device__ __forceinline__ void up2(unsigned g, float& lo, float& hi) {
    lo = __uint_as_float(g << 16);
    hi = __uint_as_float(g & 0xffff0000u);
}

__device__ __forceinline__ void edge_sd(const int* __restrict__ ei, int E, int e,
                                        int& s, int& d) {
    if (e < E) { s = ei[e]; d = ei[E + e]; }
    else       { s = e - E; d = e - E; }   // self-loop
}

// K0: dtype detect (bf16 N(0,1): u16 exp field never >=160; fp32: ~19% of words)
__global__ void k_detect(const unsigned short* __restrict__ x, int* __restrict__ flag) {
    __shared__ int sh[256];
    int cnt = 0;
    for (int i = threadIdx.x; i < 8192; i += 256)
        if (((x[i] >> 7) & 0xFF) >= 160) cnt++;
    sh[threadIdx.x] = cnt;
    __syncthreads();
    for (int s = 128; s > 0; s >>= 1) {
        if (threadIdx.x < s) sh[threadIdx.x] += sh[threadIdx.x + s];
        __syncthreads();
    }
    if (threadIdx.x == 0) flag[0] = (sh[0] < 100) ? 1 : 0;   // 1=bf16, 0=fp32
}

// K1: h1 = x @ W1 -> bf16 store; fused per-head attention scores es1/ed1 [N,4]
__global__ void k_gemm1(const void* __restrict__ x, const void* __restrict__ W1,
                        const void* __restrict__ as1, const void* __restrict__ ad1,
                        const int* __restrict__ flag, bf16* __restrict__ h1b,
                        float* __restrict__ es1, float* __restrict__ ed1, int N) {
    __shared__ float xs[BN][F1];
    const int isbf = flag[0];
    int n0 = blockIdx.x * BN, t = threadIdx.x;
    for (int i = t; i < BN * F1; i += 256) {
        int nn = i >> 7, kk = i & 127;
        int n = n0 + nn; if (n >= N) n = N - 1;
        xs[nn][kk] = ldf(x, (size_t)n * F1 + kk, isbf);
    }
    __syncthreads();
    int col = t & 127, nh = t >> 7;   // thread owns nodes nh, nh+2, nh+4, nh+6
    float a[4] = {0.f, 0.f, 0.f, 0.f};
    if (isbf) {
        const bf16* W = (const bf16*)W1;
#pragma unroll 4
        for (int k = 0; k < F1; k++) {
            float w = __bfloat162float(W[(size_t)k * F1 + col]);
            a[0] = fmaf(xs[nh][k], w, a[0]);     a[1] = fmaf(xs[nh + 2][k], w, a[1]);
            a[2] = fmaf(xs[nh + 4][k], w, a[2]); a[3] = fmaf(xs[nh + 6][k], w, a[3]);
        }
    } else {
        const float* W = (const float*)W1;
#pragma unroll 4
        for (int k = 0; k < F1; k++) {
            float w = W[(size_t)k * F1 + col];
            a[0] = fmaf(xs[nh][k], w, a[0]);     a[1] = fmaf(xs[nh + 2][k], w, a[1]);
            a[2] = fmaf(xs[nh + 4][k], w, a[2]); a[3] = fmaf(xs[nh + 6][k], w, a[3]);
        }
    }
    float asv = ldf(as1, col, isbf), adv = ldf(ad1, col, isbf);
    int h = col >> 5;
#pragma unroll
    for (int j = 0; j < 4; j++) {
        int n = n0 + nh + 2 * j;
        float s = a[j] * asv, dd = a[j] * adv;
#pragma unroll
        for (int off = 16; off > 0; off >>= 1) {
            s += __shfl_down(s, off, 32);
            dd += __shfl_down(dd, off, 32);
        }
        if (n < N) {
            h1b[(size_t)n * F1 + col] = __float2bfloat16(a[j]);
            if ((t & 31) == 0) { es1[n * H1 + h] = s; ed1[n * H1 + h] = dd; }
        }
    }
}

// K2: histogram of dst degrees
__global__ void k_hist(const int* __restrict__ ei, int E, int ET, int* __restrict__ deg) {
    int e = blockIdx.x * blockDim.x + threadIdx.x;
    if (e >= ET) return;
    int s, d; edge_sd(ei, E, e, s, d);
    atomicAdd(&deg[d], 1);
}

// K3a: per-256-chunk sums
__global__ void k_scan1(const int* __restrict__ deg, int N, int* __restrict__ part) {
    __shared__ int sh[256];
    int i = blockIdx.x * 256 + threadIdx.x;
    sh[threadIdx.x] = (i < N) ? deg[i] : 0;
    __syncthreads();
    for (int s = 128; s > 0; s >>= 1) {
        if (threadIdx.x < s) sh[threadIdx.x] += sh[threadIdx.x + s];
        __syncthreads();
    }
    if (threadIdx.x == 0) part[blockIdx.x] = sh[0];
}

// K3b: exclusive scan of partials (<=256)
__global__ void k_scan2(int* __restrict__ part, int NB) {
    __shared__ int sh[256];
    int t = threadIdx.x;
    int v = (t < NB) ? part[t] : 0;
    sh[t] = v;
    __syncthreads();
    for (int off = 1; off < 256; off <<= 1) {
        int add = (t >= off) ? sh[t - off] : 0;
        __syncthreads();
        sh[t] += add;
        __syncthreads();
    }
    if (t < NB) part[t] = sh[t] - v;   // exclusive
}

// K3c: offs = exclusive scan of deg
__global__ void k_scan3(const int* __restrict__ deg, int N, const int* __restrict__ part,
                        int* __restrict__ offs) {
    __shared__ int sh[256];
    int t = threadIdx.x, i = blockIdx.x * 256 + t;
    int v = (i < N) ? deg[i] : 0;
    sh[t] = v;
    __syncthreads();
    for (int off = 1; off < 256; off <<= 1) {
        int add = (t >= off) ? sh[t - off] : 0;
        __syncthreads();
        sh[t] += add;
        __syncthreads();
    }
    if (i < N) offs[i] = sh[t] - v + part[blockIdx.x];
}

// K4: scatter (src,dst) into CSR slots; offs[d] post-increments to segment END.
__global__ void k_scatter(const int* __restrict__ ei, int E, int ET,
                          int* __restrict__ offs, int* __restrict__ ebuf,
                          int* __restrict__ dstb) {
    int e = blockIdx.x * blockDim.x + threadIdx.x;
    if (e >= ET) return;
    int s, d; edge_sd(ei, E, e, s, d);
    int pos = atomicAdd(&offs[d], 1);
    ebuf[pos] = s;
    dstb[pos] = d;
}

// K5: per-edge layer-1 softmax numerators (4 heads) in CSR order
__global__ void k_ex1(const int* __restrict__ ebuf, const int* __restrict__ dstb,
                      const float* __restrict__ es1, const float* __restrict__ ed1,
                      float4* __restrict__ exs1, int ET) {
    int p = blockIdx.x * blockDim.x + threadIdx.x;
    if (p >= ET) return;
    int s = ebuf[p], d = dstb[p];
    float4 e = ((const float4*)es1)[s];
    float4 f = ((const float4*)ed1)[d];
    float4 r;
    r.x = __expf(lrelu(e.x + f.x));
    r.y = __expf(lrelu(e.y + f.y));
    r.z = __expf(lrelu(e.z + f.z));
    r.w = __expf(lrelu(e.w + f.w));
    exs1[p] = r;
}

// K6: layer-1 aggregate (wave per node, 2 packed cols/lane, unroll-4)
//     + normalize + bias + ELU + h2 GEMM + layer-2 scores
__global__ void __launch_bounds__(256) k_l1(
        const int* __restrict__ offs, const int* __restrict__ ebuf,
        const float* __restrict__ exs1, const bf16* __restrict__ h1b,
        const void* __restrict__ b1, const void* __restrict__ W2,
        const void* __restrict__ as2, const void* __restrict__ ad2,
        const int* __restrict__ flag, float* __restrict__ h2,
        float* __restrict__ es2, float* __restrict__ ed2, int N) {
    int w = threadIdx.x >> 6, l = threadIdx.x & 63;
    int d = blockIdx.x * 4 + w; if (d >= N) d = N - 1;   // clamp (idempotent dup)
    int start = d ? offs[d - 1] : 0, end = offs[d];
    int h = l >> 4;                       // head of cols 2l, 2l+1
    const unsigned* h1p = (const unsigned*)h1b;
    float acc0 = 0.f, acc1 = 0.f, dsum = 0.f;
    int i = start;
    for (; i + 4 <= end; i += 4) {
        int s0 = ebuf[i], s1 = ebuf[i + 1], s2 = ebuf[i + 2], s3 = ebuf[i + 3];
        float e0 = exs1[(size_t)i * 4 + h],       e1 = exs1[(size_t)(i + 1) * 4 + h];
        float e2 = exs1[(size_t)(i + 2) * 4 + h], e3 = exs1[(size_t)(i + 3) * 4 + h];
        unsigned g0 = h1p[(size_t)s0 * 64 + l], g1 = h1p[(size_t)s1 * 64 + l];
        unsigned g2 = h1p[(size_t)s2 * 64 + l], g3 = h1p[(size_t)s3 * 64 + l];
        float lo, hi;
        up2(g0, lo, hi); acc0 = fmaf(e0, lo, acc0); acc1 = fmaf(e0, hi, acc1);
        up2(g1, lo, hi); acc0 = fmaf(e1, lo, acc0); acc1 = fmaf(e1, hi, acc1);
        up2(g2, lo, hi); acc0 = fmaf(e2, lo, acc0); acc1 = fmaf(e2, hi, acc1);
        up2(g3, lo, hi); acc0 = fmaf(e3, lo, acc0); acc1 = fmaf(e3, hi, acc1);
        dsum += (e0 + e1) + (e2 + e3);
    }
    for (; i < end; i++) {
        int s0 = ebuf[i];
        float e0 = exs1[(size_t)i * 4 + h];
        float lo, hi; up2(h1p[(size_t)s0 * 64 + l], lo, hi);
        acc0 = fmaf(e0, lo, acc0); acc1 = fmaf(e0, hi, acc1);
        dsum += e0;
    }
    const int isbf = flag[0];
    float inv = 1.f / (dsum + 1e-16f);
    float v0 = acc0 * inv + ldf(b1, 2 * l, isbf);
    float v1 = acc1 * inv + ldf(b1, 2 * l + 1, isbf);
    v0 = v0 > 0.f ? v0 : (__expf(v0) - 1.f);
    v1 = v1 > 0.f ? v1 : (__expf(v1) - 1.f);
    __shared__ float hs[4][F1];
    hs[w][2 * l] = v0; hs[w][2 * l + 1] = v1;
    __syncthreads();
    float a2 = 0.f;
    if (l < C2) {
#pragma unroll 8
        for (int k = 0; k < F1; k++) a2 = fmaf(hs[w][k], ldf(W2, (size_t)k * C2 + l, isbf), a2);
        h2[(size_t)d * C2 + l] = a2;
    }
    float ps = (l < C2) ? a2 * ldf(as2, l, isbf) : 0.f;
    float pd = (l < C2) ? a2 * ldf(ad2, l, isbf) : 0.f;
#pragma unroll
    for (int off = 32; off > 0; off >>= 1) {
        ps += __shfl_xor(ps, off, 64);
        pd += __shfl_xor(pd, off, 64);
    }
    if (l == 0) { es2[d] = ps; ed2[d] = pd; }
}

// K7: per-edge layer-2 softmax numerators in CSR order
__global__ void k_ex2(const int* __restrict__ ebuf, const int* __restrict__ dstb,
                      const float* __restrict__ es2, const float* __restrict__ ed2,
                      float* __restrict__ ex2, int ET) {
    int p = blockIdx.x * blockDim.x + threadIdx.x;
    if (p >= ET) return;
    ex2[p] = __expf(lrelu(es2[ebuf[p]] + ed2[dstb[p]]));
}

// K8: layer-2 aggregate (wave per node, unroll-4) + bias + log_softmax/softmax + store
__global__ void __launch_bounds__(256) k_l2(
        const int* __restrict__ offs, const int* __restrict__ ebuf,
        const float* __restrict__ ex2, const float* __restrict__ h2,
        const void* __restrict__ b2, const int* __restrict__ flag,
        void* __restrict__ out, int N) {
    int w = threadIdx.x >> 6, l = threadIdx.x & 63;
    int d = blockIdx.x * 4 + w; if (d >= N) d = N - 1;
    int start = d ? offs[d - 1] : 0, end = offs[d];
    float acc = 0.f, dsum = 0.f;
    int i = start;
    for (; i + 4 <= end; i += 4) {
        int s0 = ebuf[i], s1 = ebuf[i + 1], s2 = ebuf[i + 2], s3 = ebuf[i + 3];
        float e0 = ex2[i], e1 = ex2[i + 1], e2 = ex2[i + 2], e3 = ex2[i + 3];
        if (l < C2) {
            acc = fmaf(e0, h2[(size_t)s0 * C2 + l], acc);
            acc = fmaf(e1, h2[(size_t)s1 * C2 + l], acc);
            acc = fmaf(e2, h2[(size_t)s2 * C2 + l], acc);
            acc = fmaf(e3, h2[(size_t)s3 * C2 + l], acc);
        }
        dsum += (e0 + e1) + (e2 + e3);
    }
    for (; i < end; i++) {
        float e0 = ex2[i];
        if (l < C2) acc = fmaf(e0, h2[(size_t)ebuf[i] * C2 + l], acc);
        dsum += e0;
    }
    const int isbf = flag[0];
    float v = (l < C2) ? acc / (dsum + 1e-16f) + ldf(b2, l, isbf) : -1e30f;
    float m = v;
#pragma unroll
    for (int off = 32; off > 0; off >>= 1) m = fmaxf(m, __shfl_xor(m, off, 64));
    float exl = (l < C2) ? __expf(v - m) : 0.f;
    float sum = exl;
#pragma unroll
    for (int off = 32; off > 0; off >>= 1) sum += __shfl_xor(sum, off, 64);
    float lse = m + __logf(sum);
    if (l < C2) {
        float ls = v - lse, sm = __expf(ls);
        size_t base = (size_t)d * C2 + l, half = (size_t)N * C2;
        if (isbf) {
            ((bf16*)out)[base]        = __float2bfloat16(ls);
            ((bf16*)out)[half + base] = __float2bfloat16(sm);
        } else {
            ((float*)out)[base]        = ls;
            ((float*)out)[half + base] = sm;
        }
    }
}

extern "C" void kernel_launch(void* const* d_in, const int* in_sizes, int n_in,
                              void* d_out, int out_size, void* d_ws, size_t ws_size,
                              hipStream_t stream) {
    const int N  = in_sizes[0] / F1;
    const int E  = in_sizes[1] / 2;
    const int ET = E + N;
    const int NB = (N + 255) / 256;

    const void* x   = d_in[0];
    const int*  ei  = (const int*)d_in[1];
    const void* W1  = d_in[2];
    const void* as1 = d_in[3];
    const void* ad1 = d_in[4];
    const void* b1  = d_in[5];
    const void* W2  = d_in[6];
    const void* as2 = d_in[7];
    const void* ad2 = d_in[8];
    const void* b2  = d_in[9];

    // ---- workspace: 116N + 7ET + 260 floats ≈ 47 MB (all slices 16B-aligned) ----
    float* ws = (float*)d_ws;
    size_t o = 0;
    bf16*  h1b  = (bf16*)(ws + o); o += (size_t)64 * N;   // 128N bf16 = 64N floats
    float* es1  = ws + o; o += (size_t)H1 * N;
    float* ed1  = ws + o; o += (size_t)H1 * N;
    float* h2   = ws + o; o += (size_t)C2 * N;
    float* es2  = ws + o; o += N;
    float* ed2  = ws + o; o += N;
    int*   deg  = (int*)(ws + o); o += N;
    int*   offs = (int*)(ws + o); o += N;
    int*   part = (int*)(ws + o); o += 256;
    int*   flag = (int*)(ws + o); o += 4;
    int*   ebuf = (int*)(ws + o); o += ET;
    int*   dstb = (int*)(ws + o); o += ET;
    float4* exs1 = (float4*)(ws + o); o += (size_t)4 * ET;
    float* ex2  = ws + o; o += ET;

    const int T = 256;
    k_detect<<<1, 256, 0, stream>>>((const unsigned short*)x, flag);
    hipMemsetAsync(deg, 0, (size_t)N * sizeof(int), stream);

    k_gemm1<<<(N + BN - 1) / BN, 256, 0, stream>>>(x, W1, as1, ad1, flag, h1b, es1, ed1, N);
    k_hist<<<(ET + T - 1) / T, T, 0, stream>>>(ei, E, ET, deg);
    k_scan1<<<NB, 256, 0, stream>>>(deg, N, part);
    k_scan2<<<1, 256, 0, stream>>>(part, NB);
    k_scan3<<<NB, 256, 0, stream>>>(deg, N, part, offs);
    k_scatter<<<(ET + T - 1) / T, T, 0, stream>>>(ei, E, ET, offs, ebuf, dstb);
    k_ex1<<<(ET + T - 1) / T, T, 0, stream>>>(ebuf, dstb, es1, ed1, exs1, ET);

    k_l1<<<(N + 3) / 4, 256, 0, stream>>>(offs, ebuf, (const float*)exs1, h1b, b1, W2,
                                          as2, ad2, flag, h2, es2, ed2, N);
    k_ex2<<<(ET + T - 1) / T, T, 0, stream>>>(ebuf, dstb, es2, ed2, ex2, ET);
    k_l2<<<(N + 3) / 4, 256, 0, stream>>>(offs, ebuf, ex2, h2, b2, flag, d_out, N);
}

// Round 6
// 359.896 us; speedup vs baseline: 2.7818x; 1.0828x over previous
//
#include <hip/hip_runtime.h>
#include <hip/hip_bf16.h>

#define F1   128   // F_IN and HEADS*HID
#define H1   4     // conv1 heads
#define C2   40    // classes
#define NEG  0.2f  // leaky relu slope
#define BN   16    // gemm1 nodes per block

typedef __hip_bfloat16 bf16;

// dtype-flexible load: isbf ? bf16[i] : fp32[i]
__device__ __forceinline__ float ldf(const void* p, size_t i, int isbf) {
    return isbf ? __bfloat162float(((const bf16*)p)[i]) : ((const float*)p)[i];
}
__device__ __forceinline__ float lrelu(float a) { return a > 0.f ? a : NEG * a; }

// unpack packed bf16x2 (low ushort = even col, high ushort = odd col)
__device__ __forceinline__ void up2(unsigned g, float& lo, float& hi) {
    lo = __uint_as_float(g << 16);
    hi = __uint_as_float(g & 0xffff0000u);
}

__device__ __forceinline__ void edge_sd(const int* __restrict__ ei, int E, int e,
                                        int& s, int& d) {
    if (e < E) { s = ei[e]; d = ei[E + e]; }
    else       { s = e - E; d = e - E; }   // self-loop
}

// K0: dtype detect (bf16 N(0,1): u16 exp field never >=160; fp32: ~19% of words)
__global__ void k_detect(const unsigned short* __restrict__ x, int* __restrict__ flag) {
    __shared__ int sh[256];
    int cnt = 0;
    for (int i = threadIdx.x; i < 8192; i += 256)
        if (((x[i] >> 7) & 0xFF) >= 160) cnt++;
    sh[threadIdx.x] = cnt;
    __syncthreads();
    for (int s = 128; s > 0; s >>= 1) {
        if (threadIdx.x < s) sh[threadIdx.x] += sh[threadIdx.x + s];
        __syncthreads();
    }
    if (threadIdx.x == 0) flag[0] = (sh[0] < 100) ? 1 : 0;   // 1=bf16, 0=fp32
}

// K1: h1 = x @ W1 -> packed bf16; fused per-head attention scores es1/ed1 [N,4]
__global__ void k_gemm1(const void* __restrict__ x, const void* __restrict__ W1,
                        const void* __restrict__ as1, const void* __restrict__ ad1,
                        const int* __restrict__ flag, bf16* __restrict__ h1b,
                        float* __restrict__ es1, float* __restrict__ ed1, int N) {
    __shared__ float xs[BN][F1];
    const int isbf = flag[0];
    int n0 = blockIdx.x * BN, t = threadIdx.x;
    for (int i = t; i < BN * F1; i += 256) {
        int nn = i >> 7, kk = i & 127;
        int n = n0 + nn; if (n >= N) n = N - 1;
        xs[nn][kk] = ldf(x, (size_t)n * F1 + kk, isbf);
    }
    __syncthreads();
    int col = t & 127, nh = t >> 7;   // thread owns nodes nh + 2j, j=0..7
    float a[8] = {0.f, 0.f, 0.f, 0.f, 0.f, 0.f, 0.f, 0.f};
    if (isbf) {
        const bf16* W = (const bf16*)W1;
#pragma unroll 4
        for (int k = 0; k < F1; k++) {
            float w = __bfloat162float(W[(size_t)k * F1 + col]);
#pragma unroll
            for (int j = 0; j < 8; j++) a[j] = fmaf(xs[nh + 2 * j][k], w, a[j]);
        }
    } else {
        const float* W = (const float*)W1;
#pragma unroll 4
        for (int k = 0; k < F1; k++) {
            float w = W[(size_t)k * F1 + col];
#pragma unroll
            for (int j = 0; j < 8; j++) a[j] = fmaf(xs[nh + 2 * j][k], w, a[j]);
        }
    }
    float asv = ldf(as1, col, isbf), adv = ldf(ad1, col, isbf);
    int h = col >> 5;
#pragma unroll
    for (int j = 0; j < 8; j++) {
        int n = n0 + nh + 2 * j;
        float s = a[j] * asv, dd = a[j] * adv;
#pragma unroll
        for (int off = 16; off > 0; off >>= 1) {
            s += __shfl_down(s, off, 32);
            dd += __shfl_down(dd, off, 32);
        }
        if (n < N) {
            h1b[(size_t)n * F1 + col] = __float2bfloat16(a[j]);
            if ((t & 31) == 0) { es1[n * H1 + h] = s; ed1[n * H1 + h] = dd; }
        }
    }
}

// K2: histogram of dst degrees
__global__ void k_hist(const int* __restrict__ ei, int E, int ET, int* __restrict__ deg) {
    int e = blockIdx.x * blockDim.x + threadIdx.x;
    if (e >= ET) return;
    int s, d; edge_sd(ei, E, e, s, d);
    atomicAdd(&deg[d], 1);
}

// K3a: per-256-chunk sums
__global__ void k_scan1(const int* __restrict__ deg, int N, int* __restrict__ part) {
    __shared__ int sh[256];
    int i = blockIdx.x * 256 + threadIdx.x;
    sh[threadIdx.x] = (i < N) ? deg[i] : 0;
    __syncthreads();
    for (int s = 128; s > 0; s >>= 1) {
        if (threadIdx.x < s) sh[threadIdx.x] += sh[threadIdx.x + s];
        __syncthreads();
    }
    if (threadIdx.x == 0) part[blockIdx.x] = sh[0];
}

// K3b: exclusive scan of partials (<=256)
__global__ void k_scan2(int* __restrict__ part, int NB) {
    __shared__ int sh[256];
    int t = threadIdx.x;
    int v = (t < NB) ? part[t] : 0;
    sh[t] = v;
    __syncthreads();
    for (int off = 1; off < 256; off <<= 1) {
        int add = (t >= off) ? sh[t - off] : 0;
        __syncthreads();
        sh[t] += add;
        __syncthreads();
    }
    if (t < NB) part[t] = sh[t] - v;   // exclusive
}

// K3c: offs = exclusive scan of deg
__global__ void k_scan3(const int* __restrict__ deg, int N, const int* __restrict__ part,
                        int* __restrict__ offs) {
    __shared__ int sh[256];
    int t = threadIdx.x, i = blockIdx.x * 256 + t;
    int v = (i < N) ? deg[i] : 0;
    sh[t] = v;
    __syncthreads();
    for (int off = 1; off < 256; off <<= 1) {
        int add = (t >= off) ? sh[t - off] : 0;
        __syncthreads();
        sh[t] += add;
        __syncthreads();
    }
    if (i < N) offs[i] = sh[t] - v + part[blockIdx.x];
}

// K4: scatter src into CSR slots + fused layer-1 softmax numerators (4 heads)
__global__ void k_scatter(const int* __restrict__ ei, int E, int ET,
                          int* __restrict__ offs, int* __restrict__ ebuf,
                          const float4* __restrict__ es1v, const float4* __restrict__ ed1v,
                          float4* __restrict__ exs1) {
    int e = blockIdx.x * blockDim.x + threadIdx.x;
    if (e >= ET) return;
    int s, d; edge_sd(ei, E, e, s, d);
    int pos = atomicAdd(&offs[d], 1);
    ebuf[pos] = s;
    float4 a = es1v[s], b = ed1v[d];
    float4 r;
    r.x = __expf(lrelu(a.x + b.x));
    r.y = __expf(lrelu(a.y + b.y));
    r.z = __expf(lrelu(a.z + b.z));
    r.w = __expf(lrelu(a.w + b.w));
    exs1[pos] = r;
}

// K5: layer-1 aggregate. Wave/node; lane (q=l>>4, c16=l&15): quarter q gathers row of
// edge i+q with ONE dwordx4 (16 lanes x 16B = 256B row). Cols [8*c16,8*c16+8) all in
// head c16>>2. Cross-quarter shuffle-reduce, then normalize+bias+ELU+W2 GEMM+L2 scores.
__global__ void __launch_bounds__(256) k_l1(
        const int* __restrict__ offs, const int* __restrict__ ebuf,
        const float* __restrict__ exs1, const uint4* __restrict__ h1p4,
        const void* __restrict__ b1, const void* __restrict__ W2,
        const void* __restrict__ as2, const void* __restrict__ ad2,
        const int* __restrict__ flag, bf16* __restrict__ h2b,
        float* __restrict__ es2, float* __restrict__ ed2, int N) {
    int w = threadIdx.x >> 6, l = threadIdx.x & 63;
    int d = blockIdx.x * 4 + w; if (d >= N) d = N - 1;   // clamp: idempotent dup
    int start = d ? offs[d - 1] : 0, end = offs[d];
    int q = l >> 4, c16 = l & 15, h = c16 >> 2;
    float acc[8] = {0.f, 0.f, 0.f, 0.f, 0.f, 0.f, 0.f, 0.f};
    float dsum = 0.f;

    auto body = [&](int base) {
        int e_i = base + q;
        int s = ebuf[e_i];
        float ev = exs1[(size_t)e_i * 4 + h];
        uint4 g = h1p4[(size_t)s * 16 + c16];
        float lo, hi;
        up2(g.x, lo, hi); acc[0] = fmaf(ev, lo, acc[0]); acc[1] = fmaf(ev, hi, acc[1]);
        up2(g.y, lo, hi); acc[2] = fmaf(ev, lo, acc[2]); acc[3] = fmaf(ev, hi, acc[3]);
        up2(g.z, lo, hi); acc[4] = fmaf(ev, lo, acc[4]); acc[5] = fmaf(ev, hi, acc[5]);
        up2(g.w, lo, hi); acc[6] = fmaf(ev, lo, acc[6]); acc[7] = fmaf(ev, hi, acc[7]);
        dsum += ev;
    };

    int i = start;
    for (; i + 8 <= end; i += 8) { body(i); body(i + 4); }
    for (; i + 4 <= end; i += 4) body(i);
    if (i < end && i + q < end) body(i);   // remainder 1..3 edges (quarters masked)

    // reduce across quarters (lane ^16, ^32 keep c16, flip q bits)
#pragma unroll
    for (int off = 16; off <= 32; off <<= 1) {
#pragma unroll
        for (int j = 0; j < 8; j++) acc[j] += __shfl_xor(acc[j], off, 64);
        dsum += __shfl_xor(dsum, off, 64);
    }

    const int isbf = flag[0];
    __shared__ float hs[4][F1];
    if (q == 0) {
        float inv = 1.f / (dsum + 1e-16f);
#pragma unroll
        for (int j = 0; j < 8; j++) {
            int col = c16 * 8 + j;
            float v = acc[j] * inv + ldf(b1, col, isbf);
            hs[w][col] = v > 0.f ? v : (__expf(v) - 1.f);   // ELU
        }
    }
    __syncthreads();
    float a2 = 0.f;
    if (l < C2) {
        if (isbf) {
            const bf16* W = (const bf16*)W2;
#pragma unroll 8
            for (int k = 0; k < F1; k++)
                a2 = fmaf(hs[w][k], __bfloat162float(W[(size_t)k * C2 + l]), a2);
        } else {
            const float* W = (const float*)W2;
#pragma unroll 8
            for (int k = 0; k < F1; k++) a2 = fmaf(hs[w][k], W[(size_t)k * C2 + l], a2);
        }
        h2b[(size_t)d * C2 + l] = __float2bfloat16(a2);
    }
    float ps = (l < C2) ? a2 * ldf(as2, l, isbf) : 0.f;
    float pd = (l < C2) ? a2 * ldf(ad2, l, isbf) : 0.f;
#pragma unroll
    for (int off = 32; off > 0; off >>= 1) {
        ps += __shfl_xor(ps, off, 64);
        pd += __shfl_xor(pd, off, 64);
    }
    if (l == 0) { es2[d] = ps; ed2[d] = pd; }
}

// K6: layer-2 aggregate, bf16 h2 rows (20 dwords), ex computed on the fly.
// Wave/node; two half-waves each process 2 edges per iteration (lanes j<20 gather).
__global__ void __launch_bounds__(256) k_l2(
        const int* __restrict__ offs, const int* __restrict__ ebuf,
        const float* __restrict__ es2, const float* __restrict__ ed2,
        const unsigned* __restrict__ h2p, const void* __restrict__ b2,
        const int* __restrict__ flag, void* __restrict__ out, int N) {
    int w = threadIdx.x >> 6, l = threadIdx.x & 63;
    int d = blockIdx.x * 4 + w; if (d >= N) d = N - 1;
    int start = d ? offs[d - 1] : 0, end = offs[d];
    float edd = ed2[d];
    int half = l >> 5, j = l & 31;
    float acc0 = 0.f, acc1 = 0.f, dsum = 0.f;
    int i = start;
    for (; i + 4 <= end; i += 4) {
        int e0 = i + half, e1 = i + 2 + half;
        int s0 = ebuf[e0], s1 = ebuf[e1];
        float x0 = __expf(lrelu(es2[s0] + edd));
        float x1 = __expf(lrelu(es2[s1] + edd));
        if (j < 20) {
            unsigned g0 = h2p[(size_t)s0 * 20 + j];
            unsigned g1 = h2p[(size_t)s1 * 20 + j];
            float lo, hi;
            up2(g0, lo, hi); acc0 = fmaf(x0, lo, acc0); acc1 = fmaf(x0, hi, acc1);
            up2(g1, lo, hi); acc0 = fmaf(x1, lo, acc0); acc1 = fmaf(x1, hi, acc1);
        }
        dsum += x0 + x1;
    }
    for (; i < end; i++) {
        int s0 = ebuf[i];
        float x0 = __expf(lrelu(es2[s0] + edd));
        if (half == 0) {
            if (j < 20) {
                float lo, hi; up2(h2p[(size_t)s0 * 20 + j], lo, hi);
                acc0 = fmaf(x0, lo, acc0); acc1 = fmaf(x0, hi, acc1);
            }
            dsum += x0;
        }
    }
    // combine halves (lane ^32)
    acc0 += __shfl_xor(acc0, 32, 64);
    acc1 += __shfl_xor(acc1, 32, 64);
    dsum += __shfl_xor(dsum, 32, 64);

    const int isbf = flag[0];
    float inv = 1.f / (dsum + 1e-16f);
    float v0 = -1e30f, v1 = -1e30f;
    if (l < 20) {
        v0 = acc0 * inv + ldf(b2, 2 * l, isbf);
        v1 = acc1 * inv + ldf(b2, 2 * l + 1, isbf);
    }
    float m = fmaxf(v0, v1);
#pragma unroll
    for (int off = 16; off > 0; off >>= 1) m = fmaxf(m, __shfl_xor(m, off, 32));
    float sv = (l < 20) ? __expf(v0 - m) + __expf(v1 - m) : 0.f;
#pragma unroll
    for (int off = 16; off > 0; off >>= 1) sv += __shfl_xor(sv, off, 32);
    float lse = m + __logf(sv);
    if (l < 20) {
        float ls0 = v0 - lse, ls1 = v1 - lse;
        size_t base = (size_t)d * C2 + 2 * l, halfo = (size_t)N * C2;
        if (isbf) {
            bf16* o = (bf16*)out;
            o[base] = __float2bfloat16(ls0);
            o[base + 1] = __float2bfloat16(ls1);
            o[halfo + base] = __float2bfloat16(__expf(ls0));
            o[halfo + base + 1] = __float2bfloat16(__expf(ls1));
        } else {
            float* o = (float*)out;
            o[base] = ls0;
            o[base + 1] = ls1;
            o[halfo + base] = __expf(ls0);
            o[halfo + base + 1] = __expf(ls1);
        }
    }
}

extern "C" void kernel_launch(void* const* d_in, const int* in_sizes, int n_in,
                              void* d_out, int out_size, void* d_ws, size_t ws_size,
                              hipStream_t stream) {
    const int N  = in_sizes[0] / F1;
    const int E  = in_sizes[1] / 2;
    const int ET = E + N;
    const int NB = (N + 255) / 256;

    const void* x   = d_in[0];
    const int*  ei  = (const int*)d_in[1];
    const void* W1  = d_in[2];
    const void* as1 = d_in[3];
    const void* ad1 = d_in[4];
    const void* b1  = d_in[5];
    const void* W2  = d_in[6];
    const void* as2 = d_in[7];
    const void* ad2 = d_in[8];
    const void* b2  = d_in[9];

    // ---- workspace: ~96N + 5ET floats ≈ 36 MB, all slices 16B-aligned ----
    float* ws = (float*)d_ws;
    auto al4 = [](size_t v) { return (v + 3) & ~(size_t)3; };
    size_t o = 0;
    bf16*  h1b  = (bf16*)(ws + o); o = al4(o + (size_t)64 * N);  // 128N bf16
    float* es1  = ws + o; o = al4(o + (size_t)H1 * N);
    float* ed1  = ws + o; o = al4(o + (size_t)H1 * N);
    bf16*  h2b  = (bf16*)(ws + o); o = al4(o + (size_t)20 * N);  // 40N bf16
    float* es2  = ws + o; o = al4(o + N);
    float* ed2  = ws + o; o = al4(o + N);
    int*   deg  = (int*)(ws + o); o = al4(o + N);
    int*   offs = (int*)(ws + o); o = al4(o + N);
    int*   part = (int*)(ws + o); o = al4(o + 256);
    int*   flag = (int*)(ws + o); o = al4(o + 4);
    int*   ebuf = (int*)(ws + o); o = al4(o + ET);
    float4* exs1 = (float4*)(ws + o); o = al4(o + (size_t)4 * ET);

    const int T = 256;
    k_detect<<<1, 256, 0, stream>>>((const unsigned short*)x, flag);
    hipMemsetAsync(deg, 0, (size_t)N * sizeof(int), stream);

    k_gemm1<<<(N + BN - 1) / BN, 256, 0, stream>>>(x, W1, as1, ad1, flag, h1b,
                                                   es1, ed1, N);
    k_hist<<<(ET + T - 1) / T, T, 0, stream>>>(ei, E, ET, deg);
    k_scan1<<<NB, 256, 0, stream>>>(deg, N, part);
    k_scan2<<<1, 256, 0, stream>>>(part, NB);
    k_scan3<<<NB, 256, 0, stream>>>(deg, N, part, offs);
    k_scatter<<<(ET + T - 1) / T, T, 0, stream>>>(ei, E, ET, offs, ebuf,
                                                  (const float4*)es1, (const float4*)ed1,
                                                  exs1);
    k_l1<<<(N + 3) / 4, 256, 0, stream>>>(offs, ebuf, (const float*)exs1,
                                          (const uint4*)h1b, b1, W2, as2, ad2, flag,
                                          h2b, es2, ed2, N);
    k_l2<<<(N + 3) / 4, 256, 0, stream>>>(offs, ebuf, es2, ed2, (const unsigned*)h2b,
                                          b2, flag, d_out, N);
}

// Round 7
// 345.136 us; speedup vs baseline: 2.9007x; 1.0428x over previous
//
#include <hip/hip_runtime.h>
#include <hip/hip_bf16.h>

#define F1   128   // F_IN and HEADS*HID
#define H1   4     // conv1 heads
#define C2   40    // classes
#define NEG  0.2f  // leaky relu slope
#define BN   16    // gemm1 nodes per block

typedef __hip_bfloat16 bf16;

// dtype-flexible load: isbf ? bf16[i] : fp32[i]
__device__ __forceinline__ float ldf(const void* p, size_t i, int isbf) {
    return isbf ? __bfloat162float(((const bf16*)p)[i]) : ((const float*)p)[i];
}
__device__ __forceinline__ float lrelu(float a) { return a > 0.f ? a : NEG * a; }

// unpack packed bf16x2 (low ushort = even col, high ushort = odd col)
__device__ __forceinline__ void up2(unsigned g, float& lo, float& hi) {
    lo = __uint_as_float(g << 16);
    hi = __uint_as_float(g & 0xffff0000u);
}

__device__ __forceinline__ void edge_sd(const int* __restrict__ ei, int E, int e,
                                        int& s, int& d) {
    if (e < E) { s = ei[e]; d = ei[E + e]; }
    else       { s = e - E; d = e - E; }   // self-loop
}

// K0: dtype detect (bf16 N(0,1): u16 exp field never >=160; fp32: ~19% of words)
__global__ void k_detect(const unsigned short* __restrict__ x, int* __restrict__ flag) {
    __shared__ int sh[256];
    int cnt = 0;
    for (int i = threadIdx.x; i < 8192; i += 256)
        if (((x[i] >> 7) & 0xFF) >= 160) cnt++;
    sh[threadIdx.x] = cnt;
    __syncthreads();
    for (int s = 128; s > 0; s >>= 1) {
        if (threadIdx.x < s) sh[threadIdx.x] += sh[threadIdx.x + s];
        __syncthreads();
    }
    if (threadIdx.x == 0) flag[0] = (sh[0] < 100) ? 1 : 0;   // 1=bf16, 0=fp32
}

// K1: h1 = x @ W1 -> packed bf16; fused attention scores es1/ed1 [N,4]
//     + fused dst-degree histogram over an edge slice (independent work)
__global__ void k_gemm1(const void* __restrict__ x, const void* __restrict__ W1,
                        const void* __restrict__ as1, const void* __restrict__ ad1,
                        const int* __restrict__ flag, const int* __restrict__ ei,
                        int E, int ET, int* __restrict__ deg,
                        bf16* __restrict__ h1b, float* __restrict__ es1,
                        float* __restrict__ ed1, int N) {
    // --- histogram slice (co-scheduled with GEMM below) ---
    int per = (ET + gridDim.x - 1) / gridDim.x;
    int he0 = blockIdx.x * per;
    int he1 = he0 + per; if (he1 > ET) he1 = ET;
    for (int e = he0 + threadIdx.x; e < he1; e += 256) {
        int d = (e < E) ? ei[E + e] : e - E;
        atomicAdd(&deg[d], 1);
    }
    // --- GEMM ---
    __shared__ float xs[BN][F1];
    const int isbf = flag[0];
    int n0 = blockIdx.x * BN, t = threadIdx.x;
    for (int i = t; i < BN * F1; i += 256) {
        int nn = i >> 7, kk = i & 127;
        int n = n0 + nn; if (n >= N) n = N - 1;
        xs[nn][kk] = ldf(x, (size_t)n * F1 + kk, isbf);
    }
    __syncthreads();
    int col = t & 127, nh = t >> 7;   // thread owns nodes nh + 2j, j=0..7
    float a[8] = {0.f, 0.f, 0.f, 0.f, 0.f, 0.f, 0.f, 0.f};
    if (isbf) {
        const bf16* W = (const bf16*)W1;
#pragma unroll 4
        for (int k = 0; k < F1; k++) {
            float w = __bfloat162float(W[(size_t)k * F1 + col]);
#pragma unroll
            for (int j = 0; j < 8; j++) a[j] = fmaf(xs[nh + 2 * j][k], w, a[j]);
        }
    } else {
        const float* W = (const float*)W1;
#pragma unroll 4
        for (int k = 0; k < F1; k++) {
            float w = W[(size_t)k * F1 + col];
#pragma unroll
            for (int j = 0; j < 8; j++) a[j] = fmaf(xs[nh + 2 * j][k], w, a[j]);
        }
    }
    float asv = ldf(as1, col, isbf), adv = ldf(ad1, col, isbf);
    int h = col >> 5;
#pragma unroll
    for (int j = 0; j < 8; j++) {
        int n = n0 + nh + 2 * j;
        float s = a[j] * asv, dd = a[j] * adv;
#pragma unroll
        for (int off = 16; off > 0; off >>= 1) {
            s += __shfl_down(s, off, 32);
            dd += __shfl_down(dd, off, 32);
        }
        if (n < N) {
            h1b[(size_t)n * F1 + col] = __float2bfloat16(a[j]);
            if ((t & 31) == 0) { es1[n * H1 + h] = s; ed1[n * H1 + h] = dd; }
        }
    }
}

// K2a: per-256-chunk sums
__global__ void k_scan1(const int* __restrict__ deg, int N, int* __restrict__ part) {
    __shared__ int sh[256];
    int i = blockIdx.x * 256 + threadIdx.x;
    sh[threadIdx.x] = (i < N) ? deg[i] : 0;
    __syncthreads();
    for (int s = 128; s > 0; s >>= 1) {
        if (threadIdx.x < s) sh[threadIdx.x] += sh[threadIdx.x + s];
        __syncthreads();
    }
    if (threadIdx.x == 0) part[blockIdx.x] = sh[0];
}

// K2b: exclusive scan of partials (<=256)
__global__ void k_scan2(int* __restrict__ part, int NB) {
    __shared__ int sh[256];
    int t = threadIdx.x;
    int v = (t < NB) ? part[t] : 0;
    sh[t] = v;
    __syncthreads();
    for (int off = 1; off < 256; off <<= 1) {
        int add = (t >= off) ? sh[t - off] : 0;
        __syncthreads();
        sh[t] += add;
        __syncthreads();
    }
    if (t < NB) part[t] = sh[t] - v;   // exclusive
}

// K2c: offs = exclusive scan of deg
__global__ void k_scan3(const int* __restrict__ deg, int N, const int* __restrict__ part,
                        int* __restrict__ offs) {
    __shared__ int sh[256];
    int t = threadIdx.x, i = blockIdx.x * 256 + t;
    int v = (i < N) ? deg[i] : 0;
    sh[t] = v;
    __syncthreads();
    for (int off = 1; off < 256; off <<= 1) {
        int add = (t >= off) ? sh[t - off] : 0;
        __syncthreads();
        sh[t] += add;
        __syncthreads();
    }
    if (i < N) offs[i] = sh[t] - v + part[blockIdx.x];
}

// K3: minimal scatter: src ids into CSR slots (offs post-increments to segment END)
__global__ void k_scatter(const int* __restrict__ ei, int E, int ET,
                          int* __restrict__ offs, int* __restrict__ ebuf) {
    int e = blockIdx.x * blockDim.x + threadIdx.x;
    if (e >= ET) return;
    int s, d; edge_sd(ei, E, e, s, d);
    int pos = atomicAdd(&offs[d], 1);
    ebuf[pos] = s;
}

// K4: layer-1 aggregate. Wave/node; lane (q=l>>4, c16=l&15): quarter q handles edge
// i+q, gathers its row with ONE dwordx4 (16 lanes x 16B = 256B). es1 gathered from
// L2-resident [N,4] array, exp computed in-loop. Cross-quarter shuffle-reduce, then
// normalize + bias + ELU + W2 GEMM + layer-2 scores.
__global__ void __launch_bounds__(256) k_l1(
        const int* __restrict__ offs, const int* __restrict__ ebuf,
        const float* __restrict__ es1, const float* __restrict__ ed1,
        const uint4* __restrict__ h1p4, const void* __restrict__ b1,
        const void* __restrict__ W2, const void* __restrict__ as2,
        const void* __restrict__ ad2, const int* __restrict__ flag,
        bf16* __restrict__ h2b, float* __restrict__ es2, float* __restrict__ ed2,
        int N) {
    int w = threadIdx.x >> 6, l = threadIdx.x & 63;
    int d = blockIdx.x * 4 + w; if (d >= N) d = N - 1;   // clamp: idempotent dup
    int start = d ? offs[d - 1] : 0, end = offs[d];
    int q = l >> 4, c16 = l & 15, h = c16 >> 2;
    float edh = ed1[d * H1 + h];
    float acc[8] = {0.f, 0.f, 0.f, 0.f, 0.f, 0.f, 0.f, 0.f};
    float dsum = 0.f;

    auto body = [&](int base) {
        int e_i = base + q;
        int s = ebuf[e_i];
        float esv = es1[s * H1 + h];                 // L2-resident gather
        uint4 g = h1p4[(size_t)s * 16 + c16];
        float ev = __expf(lrelu(esv + edh));
        float lo, hi;
        up2(g.x, lo, hi); acc[0] = fmaf(ev, lo, acc[0]); acc[1] = fmaf(ev, hi, acc[1]);
        up2(g.y, lo, hi); acc[2] = fmaf(ev, lo, acc[2]); acc[3] = fmaf(ev, hi, acc[3]);
        up2(g.z, lo, hi); acc[4] = fmaf(ev, lo, acc[4]); acc[5] = fmaf(ev, hi, acc[5]);
        up2(g.w, lo, hi); acc[6] = fmaf(ev, lo, acc[6]); acc[7] = fmaf(ev, hi, acc[7]);
        dsum += ev;
    };

    int i = start;
    for (; i + 8 <= end; i += 8) { body(i); body(i + 4); }
    for (; i + 4 <= end; i += 4) body(i);
    if (i < end && i + q < end) body(i);   // remainder 1..3 edges (quarters masked)

    // reduce across quarters (lane ^16, ^32 keep c16, flip q bits)
#pragma unroll
    for (int off = 16; off <= 32; off <<= 1) {
#pragma unroll
        for (int j = 0; j < 8; j++) acc[j] += __shfl_xor(acc[j], off, 64);
        dsum += __shfl_xor(dsum, off, 64);
    }

    const int isbf = flag[0];
    __shared__ float hs[4][F1];
    if (q == 0) {
        float inv = 1.f / (dsum + 1e-16f);
#pragma unroll
        for (int j = 0; j < 8; j++) {
            int col = c16 * 8 + j;
            float v = acc[j] * inv + ldf(b1, col, isbf);
            hs[w][col] = v > 0.f ? v : (__expf(v) - 1.f);   // ELU
        }
    }
    __syncthreads();
    float a2 = 0.f;
    if (l < C2) {
        if (isbf) {
            const bf16* W = (const bf16*)W2;
#pragma unroll 8
            for (int k = 0; k < F1; k++)
                a2 = fmaf(hs[w][k], __bfloat162float(W[(size_t)k * C2 + l]), a2);
        } else {
            const float* W = (const float*)W2;
#pragma unroll 8
            for (int k = 0; k < F1; k++) a2 = fmaf(hs[w][k], W[(size_t)k * C2 + l], a2);
        }
        h2b[(size_t)d * C2 + l] = __float2bfloat16(a2);
    }
    float ps = (l < C2) ? a2 * ldf(as2, l, isbf) : 0.f;
    float pd = (l < C2) ? a2 * ldf(ad2, l, isbf) : 0.f;
#pragma unroll
    for (int off = 32; off > 0; off >>= 1) {
        ps += __shfl_xor(ps, off, 64);
        pd += __shfl_xor(pd, off, 64);
    }
    if (l == 0) { es2[d] = ps; ed2[d] = pd; }
}

// K5: layer-2 aggregate, bf16 h2 rows (20 dwords), ex on the fly, unroll-8.
// Wave/node; two half-waves, 4 edges in flight each.
__global__ void __launch_bounds__(256) k_l2(
        const int* __restrict__ offs, const int* __restrict__ ebuf,
        const float* __restrict__ es2, const float* __restrict__ ed2,
        const unsigned* __restrict__ h2p, const void* __restrict__ b2,
        const int* __restrict__ flag, void* __restrict__ out, int N) {
    int w = threadIdx.x >> 6, l = threadIdx.x & 63;
    int d = blockIdx.x * 4 + w; if (d >= N) d = N - 1;
    int start = d ? offs[d - 1] : 0, end = offs[d];
    float edd = ed2[d];
    int half = l >> 5, j = l & 31;
    float acc0 = 0.f, acc1 = 0.f, dsum = 0.f;

    auto proc1 = [&](int e) {
        int s = ebuf[e];
        float xv = __expf(lrelu(es2[s] + edd));
        if (j < 20) {
            float lo, hi; up2(h2p[(size_t)s * 20 + j], lo, hi);
            acc0 = fmaf(xv, lo, acc0); acc1 = fmaf(xv, hi, acc1);
        }
        dsum += xv;
    };

    int i = start;
    for (; i + 8 <= end; i += 8) {
        int b = i + half * 4;
        int s0 = ebuf[b], s1 = ebuf[b + 1], s2 = ebuf[b + 2], s3 = ebuf[b + 3];
        float x0 = __expf(lrelu(es2[s0] + edd));
        float x1 = __expf(lrelu(es2[s1] + edd));
        float x2 = __expf(lrelu(es2[s2] + edd));
        float x3 = __expf(lrelu(es2[s3] + edd));
        if (j < 20) {
            unsigned g0 = h2p[(size_t)s0 * 20 + j], g1 = h2p[(size_t)s1 * 20 + j];
            unsigned g2 = h2p[(size_t)s2 * 20 + j], g3 = h2p[(size_t)s3 * 20 + j];
            float lo, hi;
            up2(g0, lo, hi); acc0 = fmaf(x0, lo, acc0); acc1 = fmaf(x0, hi, acc1);
            up2(g1, lo, hi); acc0 = fmaf(x1, lo, acc0); acc1 = fmaf(x1, hi, acc1);
            up2(g2, lo, hi); acc0 = fmaf(x2, lo, acc0); acc1 = fmaf(x2, hi, acc1);
            up2(g3, lo, hi); acc0 = fmaf(x3, lo, acc0); acc1 = fmaf(x3, hi, acc1);
        }
        dsum += (x0 + x1) + (x2 + x3);
    }
    for (; i + 2 <= end; i += 2) proc1(i + half);
    if (i < end && half == 0) proc1(i);

    // combine halves (lane ^32)
    acc0 += __shfl_xor(acc0, 32, 64);
    acc1 += __shfl_xor(acc1, 32, 64);
    dsum += __shfl_xor(dsum, 32, 64);

    const int isbf = flag[0];
    float inv = 1.f / (dsum + 1e-16f);
    float v0 = -1e30f, v1 = -1e30f;
    if (l < 20) {
        v0 = acc0 * inv + ldf(b2, 2 * l, isbf);
        v1 = acc1 * inv + ldf(b2, 2 * l + 1, isbf);
    }
    float m = fmaxf(v0, v1);
#pragma unroll
    for (int off = 16; off > 0; off >>= 1) m = fmaxf(m, __shfl_xor(m, off, 32));
    float sv = (l < 20) ? __expf(v0 - m) + __expf(v1 - m) : 0.f;
#pragma unroll
    for (int off = 16; off > 0; off >>= 1) sv += __shfl_xor(sv, off, 32);
    float lse = m + __logf(sv);
    if (l < 20) {
        float ls0 = v0 - lse, ls1 = v1 - lse;
        size_t base = (size_t)d * C2 + 2 * l, halfo = (size_t)N * C2;
        if (isbf) {
            bf16* o = (bf16*)out;
            o[base] = __float2bfloat16(ls0);
            o[base + 1] = __float2bfloat16(ls1);
            o[halfo + base] = __float2bfloat16(__expf(ls0));
            o[halfo + base + 1] = __float2bfloat16(__expf(ls1));
        } else {
            float* o = (float*)out;
            o[base] = ls0;
            o[base + 1] = ls1;
            o[halfo + base] = __expf(ls0);
            o[halfo + base + 1] = __expf(ls1);
        }
    }
}

extern "C" void kernel_launch(void* const* d_in, const int* in_sizes, int n_in,
                              void* d_out, int out_size, void* d_ws, size_t ws_size,
                              hipStream_t stream) {
    const int N  = in_sizes[0] / F1;
    const int E  = in_sizes[1] / 2;
    const int ET = E + N;
    const int NB = (N + 255) / 256;

    const void* x   = d_in[0];
    const int*  ei  = (const int*)d_in[1];
    const void* W1  = d_in[2];
    const void* as1 = d_in[3];
    const void* ad1 = d_in[4];
    const void* b1  = d_in[5];
    const void* W2  = d_in[6];
    const void* as2 = d_in[7];
    const void* ad2 = d_in[8];
    const void* b2  = d_in[9];

    // ---- workspace: ~92N + ET floats ≈ 22 MB, all slices 16B-aligned ----
    float* ws = (float*)d_ws;
    auto al4 = [](size_t v) { return (v + 3) & ~(size_t)3; };
    size_t o = 0;
    bf16*  h1b  = (bf16*)(ws + o); o = al4(o + (size_t)64 * N);  // 128N bf16
    float* es1  = ws + o; o = al4(o + (size_t)H1 * N);
    float* ed1  = ws + o; o = al4(o + (size_t)H1 * N);
    bf16*  h2b  = (bf16*)(ws + o); o = al4(o + (size_t)20 * N);  // 40N bf16
    float* es2  = ws + o; o = al4(o + N);
    float* ed2  = ws + o; o = al4(o + N);
    int*   deg  = (int*)(ws + o); o = al4(o + N);
    int*   offs = (int*)(ws + o); o = al4(o + N);
    int*   part = (int*)(ws + o); o = al4(o + 256);
    int*   flag = (int*)(ws + o); o = al4(o + 4);
    int*   ebuf = (int*)(ws + o); o = al4(o + ET);

    const int T = 256;
    k_detect<<<1, 256, 0, stream>>>((const unsigned short*)x, flag);
    hipMemsetAsync(deg, 0, (size_t)N * sizeof(int), stream);

    k_gemm1<<<(N + BN - 1) / BN, 256, 0, stream>>>(x, W1, as1, ad1, flag, ei, E, ET,
                                                   deg, h1b, es1, ed1, N);
    k_scan1<<<NB, 256, 0, stream>>>(deg, N, part);
    k_scan2<<<1, 256, 0, stream>>>(part, NB);
    k_scan3<<<NB, 256, 0, stream>>>(deg, N, part, offs);
    k_scatter<<<(ET + T - 1) / T, T, 0, stream>>>(ei, E, ET, offs, ebuf);
    k_l1<<<(N + 3) / 4, 256, 0, stream>>>(offs, ebuf, es1, ed1, (const uint4*)h1b,
                                          b1, W2, as2, ad2, flag, h2b, es2, ed2, N);
    k_l2<<<(N + 3) / 4, 256, 0, stream>>>(offs, ebuf, es2, ed2, (const unsigned*)h2b,
                                          b2, flag, d_out, N);
}